// Round 9
// baseline (202.793 us; speedup 1.0000x reference)
//
#include <hip/hip_runtime.h>

// ---------------------------------------------------------------------------
// AttentionAugmentedConv2d: B=8, CIN=256, COUT=512, DK=DV=256, NH=8, H=W=32
//  k_prep   : fused k_xt (padded transpose of x) + k_wconv (weight reorder)
//  k_gemm0  : implicit-GEMM fused conv (128M x 64N, BK=64, 1024 blocks)
//  k_attn   : MFMA flash attention v5: 2 key-tiles per iteration (two
//             independent mfma/exp chains per wave), no online max
//             (logits << 88, fp32-safe), XCD-swizzled grid. v4 lesson: deep
//             pipelines spill at VGPR<=128 -> consume d[] immediately.
//  k_tr     : attT [256][8192] -> attt [8192][256]
//  k_gemm_s : 1x1 conv GEMM -> out ch 256..511
// reshape trap: att channel = h*32 + y, spatial = (x, d)
// ---------------------------------------------------------------------------

typedef __attribute__((ext_vector_type(8))) short short8;
typedef __attribute__((ext_vector_type(4))) float floatx4;

__device__ __forceinline__ unsigned short f2bf(float f) {
    unsigned int u = __float_as_uint(f);
    u += 0x7FFFu + ((u >> 16) & 1u);   // round-to-nearest-even
    return (unsigned short)(u >> 16);
}
__device__ __forceinline__ float bf2f(unsigned short s) {
    return __uint_as_float(((unsigned int)s) << 16);
}
__device__ __forceinline__ unsigned int pk2bf_trunc(float lo, float hi) {
    return (__float_as_uint(lo) >> 16) | (__float_as_uint(hi) & 0xFFFF0000u);
}
__device__ __forceinline__ unsigned int pk2bf_rne(float lo, float hi) {
    return (unsigned int)f2bf(lo) | ((unsigned int)f2bf(hi) << 16);
}
__device__ __forceinline__ void gload_lds16(const unsigned short* g, unsigned short* s) {
    __builtin_amdgcn_global_load_lds(
        (const __attribute__((address_space(1))) unsigned int*)g,
        (__attribute__((address_space(3))) unsigned int*)s, 16, 0, 0);
}

// ---------------- k_prep: fused Xt transpose + weight convert ---------------
__global__ __launch_bounds__(256) void k_prep(const float* __restrict__ x,
                                              const float* __restrict__ wc,
                                              const float* __restrict__ wq,
                                              const float* __restrict__ wa,
                                              const float* __restrict__ krw,
                                              const float* __restrict__ krh,
                                              unsigned short* __restrict__ Xt,
                                              unsigned short* __restrict__ wt,
                                              unsigned short* __restrict__ wt2,
                                              unsigned short* __restrict__ krwb,
                                              unsigned short* __restrict__ krhb) {
    __shared__ char smem[16896];
    const int tid = threadIdx.x;
    const int blk = blockIdx.x;
    if (blk < 272) {
        // Xt[b][yy][xx][ci] = x[b][ci][yy-1][xx-1], zero pads
        unsigned short* lds = (unsigned short*)smem;   // [ci][x] stride 33
        const int yy = blk % 34;
        const int b  = blk / 34;
        unsigned int* outp = (unsigned int*)(Xt + (((size_t)b * 34 + yy) * 34) * 256);
        if (yy == 0 || yy == 33) {
            for (int i = tid; i < 4352; i += 256) outp[i] = 0;
            return;
        }
        const int y = yy - 1;
        const float* xb = x + (size_t)b * 262144 + y * 32;
#pragma unroll
        for (int it = 0; it < 32; ++it) {
            const int e = it * 256 + tid;
            const int ci = e >> 5, xx = e & 31;
            lds[ci * 33 + xx] = f2bf(xb[ci * 1024 + xx]);
        }
        __syncthreads();
        const int ci2 = (tid & 127) * 2;
        const int xh = tid >> 7;
#pragma unroll
        for (int it = 0; it < 17; ++it) {
            const int xx = xh * 17 + it;
            unsigned int v = 0;
            if (xx >= 1 && xx <= 32)
                v = (unsigned int)lds[ci2 * 33 + xx - 1] |
                    ((unsigned int)lds[(ci2 + 1) * 33 + xx - 1] << 16);
            outp[xx * 128 + (tid & 127)] = v;
        }
    } else if (blk < 1296) {
        // wt[n][k'], k' = g*256+ci, g = ky*3+kx; src k = ci*9+g
        float* lw = (float*)smem;
        const int n = blk - 272;
        const float* src = (n < 256) ? (wc + (size_t)n * 2304)
                                     : (wq + (size_t)(n - 256) * 2304);
#pragma unroll
        for (int it = 0; it < 9; ++it)
            lw[it * 256 + tid] = src[it * 256 + tid];
        __syncthreads();
#pragma unroll
        for (int it = 0; it < 9; ++it) {
            const int kp = it * 256 + tid;
            const int g = kp >> 8, ci = kp & 255;
            wt[(size_t)n * 2304 + kp] = f2bf(lw[ci * 9 + g]);
        }
    } else {
        const int i = (blk - 1296) * 256 + tid;
        if (i < 65536)        wt2[i] = f2bf(wa[i]);
        else if (i < 67584) { const int j = i - 65536;
                              krwb[j] = (j < 2016) ? f2bf(krw[j]) : (unsigned short)0; }
        else if (i < 69632) { const int j = i - 67584;
                              krhb[j] = (j < 2016) ? f2bf(krh[j]) : (unsigned short)0; }
    }
}

// --------------- implicit-GEMM fused conv, 128M x 64N, BK=64 ----------------
__global__ __launch_bounds__(256, 4) void k_gemm0(const unsigned short* __restrict__ Wr,
                                                  const unsigned short* __restrict__ Xt,
                                                  float* __restrict__ out,
                                                  unsigned short* __restrict__ qT,
                                                  unsigned short* __restrict__ kT,
                                                  unsigned short* __restrict__ vT,
                                                  const float* __restrict__ bias_a,
                                                  const float* __restrict__ bias_b) {
    __shared__ unsigned short As[64 * 64];
    __shared__ unsigned short Bs[128 * 64];
    const int tid = threadIdx.x;
    const int lane = tid & 63, wv = tid >> 6;
    const int l15 = lane & 15, quad = lane >> 4;
    const int m0 = blockIdx.x * 128, n0 = blockIdx.y * 64;
    const int wave_m = (wv & 1) * 64, wave_n = (wv >> 1) * 32;
    floatx4 acc[2][4] = {};
    const int lr = lane >> 3;
    const int swz8 = ((lane & 7) ^ lr) * 8;
    const unsigned short* gA = Wr + (size_t)(n0 + wv * 16 + lr) * 2304 + swz8;
    int bb0[4];
#pragma unroll
    for (int r = 0; r < 4; ++r) {
        const int m = m0 + wv * 32 + r * 8 + lr;
        const int b = m >> 10, p = m & 1023, y = p >> 5, x = p & 31;
        bb0[r] = ((b * 34 + y) * 34 + x) * 256;
    }
    unsigned short* sA0 = As + wv * 1024;
    unsigned short* sB0 = Bs + wv * 2048;
    const int sw0 = ((quad)     ^ (l15 & 7)) * 8;
    const int sw1 = ((4 + quad) ^ (l15 & 7)) * 8;
    for (int k0 = 0; k0 < 2304; k0 += 64) {
        const int g = k0 >> 8;
        const int ci0 = k0 & 255;
        const int ky = g / 3, kx = g - ky * 3;
        const int offu = (ky * 34 + kx) * 256 + ci0 + swz8;
        __syncthreads();
        gload_lds16(gA + k0, sA0);
        gload_lds16(gA + (size_t)8 * 2304 + k0, sA0 + 512);
#pragma unroll
        for (int r = 0; r < 4; ++r)
            gload_lds16(Xt + bb0[r] + offu, sB0 + r * 512);
        __syncthreads();
#pragma unroll
        for (int h = 0; h < 2; ++h) {
            const int sw = h ? sw1 : sw0;
            short8 a[2], b[4];
#pragma unroll
            for (int i = 0; i < 2; ++i)
                a[i] = *reinterpret_cast<const short8*>(As + (wave_n + i * 16 + l15) * 64 + sw);
#pragma unroll
            for (int j = 0; j < 4; ++j)
                b[j] = *reinterpret_cast<const short8*>(Bs + (wave_m + j * 16 + l15) * 64 + sw);
#pragma unroll
            for (int i = 0; i < 2; ++i)
#pragma unroll
                for (int j = 0; j < 4; ++j)
                    acc[i][j] = __builtin_amdgcn_mfma_f32_16x16x32_bf16(a[i], b[j], acc[i][j], 0, 0, 0);
        }
    }
#pragma unroll
    for (int i = 0; i < 2; ++i)
#pragma unroll
        for (int jj = 0; jj < 4; ++jj)
#pragma unroll
            for (int rg = 0; rg < 4; ++rg) {
                const int n = n0 + wave_n + i * 16 + quad * 4 + rg;
                const int m = m0 + wave_m + jj * 16 + l15;
                const float v = acc[i][jj][rg];
                const int bb = m >> 10, p = m & 1023;
                if (n < 256) {
                    out[(size_t)bb * 524288 + (size_t)n * 1024 + p] = v + bias_a[n];
                } else {
                    const int c = n - 256;
                    const float vq = v + bias_b[c];
                    if (c < 256) {
                        const int h = c >> 5, d = c & 31;
                        qT[(((size_t)(bb * 8 + h)) * 1024 + p) * 32 + d] =
                            f2bf(vq * 0.17677669529663687f);
                    } else if (c < 512) {
                        const int c2 = c - 256;
                        const int h = c2 >> 5, d = c2 & 31;
                        kT[(((size_t)(bb * 8 + h)) * 1024 + p) * 32 + d] = f2bf(vq);
                    } else {
                        const int c2 = c - 512;
                        const int h = c2 >> 5, d = c2 & 31;
                        vT[(((size_t)(bb * 8 + h)) * 32 + d) * 1024 + p] = f2bf(vq);
                    }
                }
            }
}

// --------------- MFMA flash attention v5: 2 key-tiles / iteration -----------
// bid = qt*64 + bh (XCD locality). No online max. Per iteration: 8 indep QK
// mfma (2 tiles), 2 exp streams, ONE lgkm drain, 8 PV mfma, K/V loads with a
// full 2-tile body of distance. d[] consumed immediately to bound VGPR.
__global__ __launch_bounds__(256, 4) void k_attn(const unsigned short* __restrict__ qT,
                                                 const unsigned short* __restrict__ kT,
                                                 const unsigned short* __restrict__ vT,
                                                 const unsigned short* __restrict__ krwb,
                                                 const unsigned short* __restrict__ krhb,
                                                 unsigned short* __restrict__ attT) {
    __shared__ float rh_s[64 * 68];            // [q_local][m'] stride 68 fp32
    __shared__ unsigned short Pw[4 * 2304];    // per-wave: 2 buffers of 1152
    const int tid = threadIdx.x;
    const int lane = tid & 63, wv = tid >> 6;
    const int l15 = lane & 15, quad = lane >> 4;
    const int bid = blockIdx.x;
    const int bh = bid & 63;                   // XCD swizzle: bid%8 == h
    const int qt = bid >> 6;
    const int h = bh & 7;
    const int b = bh >> 3;
    const unsigned short* qbase = qT + (size_t)bh * 32768;
    const unsigned short* kbase = kT + (size_t)bh * 32768;
    const unsigned short* vbase = vT + (size_t)bh * 32768;
    const int qloc = wv * 16 + l15;
    const int pq = qt * 64 + qloc;
    const int yq = pq >> 5, xq = pq & 31;

    const short8 qfrag = *reinterpret_cast<const short8*>(
        qbase + (size_t)pq * 32 + quad * 8);
    const floatx4 zero = {0.f, 0.f, 0.f, 0.f};
    unsigned short* pwA = Pw + wv * 2304;
    unsigned short* pwB = pwA + 1152;

    // rel tables via mfma: Rel[m'][q] = krX[m'] . Q[q]
#pragma unroll
    for (int sub = 0; sub < 4; ++sub) {
        const short8 aw = *reinterpret_cast<const short8*>(krwb + (sub * 16 + l15) * 32 + quad * 8);
        const short8 ah = *reinterpret_cast<const short8*>(krhb + (sub * 16 + l15) * 32 + quad * 8);
        const floatx4 dw = __builtin_amdgcn_mfma_f32_16x16x32_bf16(aw, qfrag, zero, 0, 0, 0);
        const floatx4 dh = __builtin_amdgcn_mfma_f32_16x16x32_bf16(ah, qfrag, zero, 0, 0, 0);
        *reinterpret_cast<floatx4*>(rh_s + qloc * 68 + sub * 16 + quad * 4) = dh;
        uint2 uu;
        uu.x = pk2bf_rne(dw[0], dw[1]);
        uu.y = pk2bf_rne(dw[2], dw[3]);
        *reinterpret_cast<uint2*>(pwA + l15 * 64 + sub * 16 + quad * 4) = uu;
    }
    float rwreg[8];
#pragma unroll
    for (int j = 0; j < 8; ++j) {
        const int xn = (j >> 2) * 16 + quad * 4 + (j & 3);
        rwreg[j] = bf2f(pwA[l15 * 64 + xn - xq + 31]);
    }
    asm volatile("s_waitcnt lgkmcnt(0)" ::: "memory");  // pwA safe to reuse

    const float* rhq = rh_s + qloc * 68 + 31 - yq;
    float lsum = 0.f;
    floatx4 O0 = zero, O1 = zero;              // O[d][q]: d=quad*4+r (+16), q=l15

    short8 kfa[4], kfb[4], vfa[4], vfb[4];
    // prologue: K/V for tiles 0 (a) and 1 (b)
#pragma unroll
    for (int sub = 0; sub < 4; ++sub) {
        kfa[sub] = *reinterpret_cast<const short8*>(
            kbase + (size_t)(sub * 16 + l15) * 32 + quad * 8);
        kfb[sub] = *reinterpret_cast<const short8*>(
            kbase + (size_t)(64 + sub * 16 + l15) * 32 + quad * 8);
    }
    vfa[0] = *reinterpret_cast<const short8*>(vbase + (size_t)l15 * 1024 + quad * 8);
    vfa[1] = *reinterpret_cast<const short8*>(vbase + (size_t)(16 + l15) * 1024 + quad * 8);
    vfa[2] = *reinterpret_cast<const short8*>(vbase + (size_t)l15 * 1024 + 32 + quad * 8);
    vfa[3] = *reinterpret_cast<const short8*>(vbase + (size_t)(16 + l15) * 1024 + 32 + quad * 8);
    vfb[0] = *reinterpret_cast<const short8*>(vbase + (size_t)l15 * 1024 + 64 + quad * 8);
    vfb[1] = *reinterpret_cast<const short8*>(vbase + (size_t)(16 + l15) * 1024 + 64 + quad * 8);
    vfb[2] = *reinterpret_cast<const short8*>(vbase + (size_t)l15 * 1024 + 96 + quad * 8);
    vfb[3] = *reinterpret_cast<const short8*>(vbase + (size_t)(16 + l15) * 1024 + 96 + quad * 8);

    for (int it = 0; it < 8; ++it) {
        const int n0a = it * 128;
        // QK both tiles: 8 independent mfma
        floatx4 da[4], db[4];
#pragma unroll
        for (int sub = 0; sub < 4; ++sub)
            da[sub] = __builtin_amdgcn_mfma_f32_16x16x32_bf16(kfa[sub], qfrag, zero, 0, 0, 0);
#pragma unroll
        for (int sub = 0; sub < 4; ++sub)
            db[sub] = __builtin_amdgcn_mfma_f32_16x16x32_bf16(kfb[sub], qfrag, zero, 0, 0, 0);
        // prefetch next iteration's K (full body of distance)
        const int nk = (it < 7) ? n0a + 128 : n0a;
#pragma unroll
        for (int sub = 0; sub < 4; ++sub) {
            kfa[sub] = *reinterpret_cast<const short8*>(
                kbase + (size_t)(nk + sub * 16 + l15) * 32 + quad * 8);
            kfb[sub] = *reinterpret_cast<const short8*>(
                kbase + (size_t)(nk + 64 + sub * 16 + l15) * 32 + quad * 8);
        }
        // exp/pack/write, tile a then tile b (d consumed immediately)
        const float rhA0 = rhq[it * 4],     rhA1 = rhq[it * 4 + 1];
        const float rhB0 = rhq[it * 4 + 2], rhB1 = rhq[it * 4 + 3];
#pragma unroll
        for (int sub = 0; sub < 4; ++sub) {
            const float rhv = (sub >> 1) ? rhA1 : rhA0;
            const float p0 = __expf(da[sub][0] + rwreg[(sub & 1) * 4 + 0] + rhv);
            const float p1 = __expf(da[sub][1] + rwreg[(sub & 1) * 4 + 1] + rhv);
            const float p2 = __expf(da[sub][2] + rwreg[(sub & 1) * 4 + 2] + rhv);
            const float p3 = __expf(da[sub][3] + rwreg[(sub & 1) * 4 + 3] + rhv);
            lsum += (p0 + p1) + (p2 + p3);
            uint2 uu;
            uu.x = pk2bf_trunc(p0, p1);
            uu.y = pk2bf_trunc(p2, p3);
            *reinterpret_cast<uint2*>(pwA + l15 * 72 + sub * 16 + quad * 4) = uu;
        }
#pragma unroll
        for (int sub = 0; sub < 4; ++sub) {
            const float rhv = (sub >> 1) ? rhB1 : rhB0;
            const float p0 = __expf(db[sub][0] + rwreg[(sub & 1) * 4 + 0] + rhv);
            const float p1 = __expf(db[sub][1] + rwreg[(sub & 1) * 4 + 1] + rhv);
            const float p2 = __expf(db[sub][2] + rwreg[(sub & 1) * 4 + 2] + rhv);
            const float p3 = __expf(db[sub][3] + rwreg[(sub & 1) * 4 + 3] + rhv);
            lsum += (p0 + p1) + (p2 + p3);
            uint2 uu;
            uu.x = pk2bf_trunc(p0, p1);
            uu.y = pk2bf_trunc(p2, p3);
            *reinterpret_cast<uint2*>(pwB + l15 * 72 + sub * 16 + quad * 4) = uu;
        }
        asm volatile("s_waitcnt lgkmcnt(0)" ::: "memory");
        const short8 pfa0 = *reinterpret_cast<const short8*>(pwA + l15 * 72 + quad * 8);
        const short8 pfa1 = *reinterpret_cast<const short8*>(pwA + l15 * 72 + 32 + quad * 8);
        const short8 pfb0 = *reinterpret_cast<const short8*>(pwB + l15 * 72 + quad * 8);
        const short8 pfb1 = *reinterpret_cast<const short8*>(pwB + l15 * 72 + 32 + quad * 8);
        // PV both tiles: 8 mfma
        O0 = __builtin_amdgcn_mfma_f32_16x16x32_bf16(vfa[0], pfa0, O0, 0, 0, 0);
        O1 = __builtin_amdgcn_mfma_f32_16x16x32_bf16(vfa[1], pfa0, O1, 0, 0, 0);
        O0 = __builtin_amdgcn_mfma_f32_16x16x32_bf16(vfa[2], pfa1, O0, 0, 0, 0);
        O1 = __builtin_amdgcn_mfma_f32_16x16x32_bf16(vfa[3], pfa1, O1, 0, 0, 0);
        O0 = __builtin_amdgcn_mfma_f32_16x16x32_bf16(vfb[0], pfb0, O0, 0, 0, 0);
        O1 = __builtin_amdgcn_mfma_f32_16x16x32_bf16(vfb[1], pfb0, O1, 0, 0, 0);
        O0 = __builtin_amdgcn_mfma_f32_16x16x32_bf16(vfb[2], pfb1, O0, 0, 0, 0);
        O1 = __builtin_amdgcn_mfma_f32_16x16x32_bf16(vfb[3], pfb1, O1, 0, 0, 0);
        // prefetch next iteration's V
        vfa[0] = *reinterpret_cast<const short8*>(vbase + (size_t)l15 * 1024 + nk + quad * 8);
        vfa[1] = *reinterpret_cast<const short8*>(vbase + (size_t)(16 + l15) * 1024 + nk + quad * 8);
        vfa[2] = *reinterpret_cast<const short8*>(vbase + (size_t)l15 * 1024 + nk + 32 + quad * 8);
        vfa[3] = *reinterpret_cast<const short8*>(vbase + (size_t)(16 + l15) * 1024 + nk + 32 + quad * 8);
        vfb[0] = *reinterpret_cast<const short8*>(vbase + (size_t)l15 * 1024 + nk + 64 + quad * 8);
        vfb[1] = *reinterpret_cast<const short8*>(vbase + (size_t)(16 + l15) * 1024 + nk + 64 + quad * 8);
        vfb[2] = *reinterpret_cast<const short8*>(vbase + (size_t)l15 * 1024 + nk + 96 + quad * 8);
        vfb[3] = *reinterpret_cast<const short8*>(vbase + (size_t)(16 + l15) * 1024 + nk + 96 + quad * 8);
    }
    lsum += __shfl_xor(lsum, 16);
    lsum += __shfl_xor(lsum, 32);
    const float inv = 1.0f / lsum;
    // coalesced output: attT[ci=h*32+yq][m2=b*1024+xq*32+d]
    unsigned short* ob = attT + ((size_t)(h * 32 + yq)) * 8192 + b * 1024 + xq * 32;
    uint2 o0, o1;
    o0.x = pk2bf_rne(O0[0] * inv, O0[1] * inv);
    o0.y = pk2bf_rne(O0[2] * inv, O0[3] * inv);
    o1.x = pk2bf_rne(O1[0] * inv, O1[1] * inv);
    o1.y = pk2bf_rne(O1[2] * inv, O1[3] * inv);
    *reinterpret_cast<uint2*>(ob + quad * 4) = o0;
    *reinterpret_cast<uint2*>(ob + 16 + quad * 4) = o1;
}

// --------------- attT [256][8192] -> attt [8192][256] -----------------------
__global__ __launch_bounds__(256) void k_tr(const unsigned short* __restrict__ src,
                                            unsigned short* __restrict__ dst) {
    __shared__ unsigned short t[64 * 72];
    const int tid = threadIdx.x;
    const int m0 = (blockIdx.x & 127) * 64;
    const int k0 = (blockIdx.x >> 7) * 64;
#pragma unroll
    for (int i = 0; i < 2; ++i) {
        const int idx = i * 256 + tid;
        const int k = idx >> 3, c8 = (idx & 7) * 8;
        *reinterpret_cast<uint4*>(t + k * 72 + c8) =
            *reinterpret_cast<const uint4*>(src + (size_t)(k0 + k) * 8192 + m0 + c8);
    }
    __syncthreads();
#pragma unroll
    for (int i = 0; i < 2; ++i) {
        const int idx = i * 256 + tid;
        const int m = idx >> 3, c8 = (idx & 7) * 8;
        unsigned short v[8];
#pragma unroll
        for (int j = 0; j < 8; ++j) v[j] = t[(c8 + j) * 72 + m];
        *reinterpret_cast<uint4*>(dst + (size_t)(m0 + m) * 256 + k0 + c8) =
            *reinterpret_cast<uint4*>(v);
    }
}

// --------------- small 64-tile GEMM for the 1x1 conv ------------------------
__global__ __launch_bounds__(256) void k_gemm_s(const unsigned short* __restrict__ Wm,
                                                const unsigned short* __restrict__ Dm,
                                                float* __restrict__ out,
                                                const float* __restrict__ bias) {
    __shared__ unsigned short As[64 * 40];
    __shared__ unsigned short Bs[64 * 40];
    const int tid = threadIdx.x;
    const int m0 = blockIdx.x * 64, n0 = blockIdx.y * 64;
    const int lane = tid & 63;
    const int wv = tid >> 6;
    const int l15 = lane & 15, quad = lane >> 4;
    const int n_off = (wv & 1) * 32, m_off = (wv >> 1) * 32;
    floatx4 acc[2][2] = {};
    const int r = tid >> 2, c8 = (tid & 3) * 8;
    const unsigned short* gA = Wm + (size_t)(n0 + r) * 256 + c8;
    const unsigned short* gB = Dm + (size_t)(m0 + r) * 256 + c8;
    unsigned short* sA = As + r * 40 + c8;
    unsigned short* sB = Bs + r * 40 + c8;
    for (int k0 = 0; k0 < 256; k0 += 32) {
        __syncthreads();
        *reinterpret_cast<uint4*>(sA) = *reinterpret_cast<const uint4*>(gA + k0);
        *reinterpret_cast<uint4*>(sB) = *reinterpret_cast<const uint4*>(gB + k0);
        __syncthreads();
        const short8 a0 = *reinterpret_cast<const short8*>(As + (n_off +      l15) * 40 + quad * 8);
        const short8 a1 = *reinterpret_cast<const short8*>(As + (n_off + 16 + l15) * 40 + quad * 8);
        const short8 b0 = *reinterpret_cast<const short8*>(Bs + (m_off +      l15) * 40 + quad * 8);
        const short8 b1 = *reinterpret_cast<const short8*>(Bs + (m_off + 16 + l15) * 40 + quad * 8);
        acc[0][0] = __builtin_amdgcn_mfma_f32_16x16x32_bf16(a0, b0, acc[0][0], 0, 0, 0);
        acc[0][1] = __builtin_amdgcn_mfma_f32_16x16x32_bf16(a0, b1, acc[0][1], 0, 0, 0);
        acc[1][0] = __builtin_amdgcn_mfma_f32_16x16x32_bf16(a1, b0, acc[1][0], 0, 0, 0);
        acc[1][1] = __builtin_amdgcn_mfma_f32_16x16x32_bf16(a1, b1, acc[1][1], 0, 0, 0);
    }
#pragma unroll
    for (int i = 0; i < 2; ++i)
#pragma unroll
        for (int jj = 0; jj < 2; ++jj)
#pragma unroll
            for (int rg = 0; rg < 4; ++rg) {
                const int n = n0 + n_off + i * 16 + quad * 4 + rg;
                const int m = m0 + m_off + jj * 16 + l15;
                const int bb = m >> 10, p = m & 1023;
                out[(size_t)bb * 524288 + (size_t)(n + 256) * 1024 + p] =
                    acc[i][jj][rg] + bias[n];
            }
}

// ---------------------------------------------------------------------------
extern "C" void kernel_launch(void* const* d_in, const int* in_sizes, int n_in,
                              void* d_out, int out_size, void* d_ws, size_t ws_size,
                              hipStream_t stream) {
    const float* x      = (const float*)d_in[0];
    const float* w_conv = (const float*)d_in[1];
    const float* b_conv = (const float*)d_in[2];
    const float* w_qkv  = (const float*)d_in[3];
    const float* b_qkv  = (const float*)d_in[4];
    const float* w_att  = (const float*)d_in[5];
    const float* b_att  = (const float*)d_in[6];
    const float* krw    = (const float*)d_in[7];
    const float* krh    = (const float*)d_in[8];
    float* out = (float*)d_out;

    char* ws = (char*)d_ws;
    unsigned short* Xt    = (unsigned short*)(ws);              //  4,734,976 B
    unsigned short* wt    = (unsigned short*)(ws + 9470464);    //  4,718,592 B
    unsigned short* wt2   = (unsigned short*)(ws + 14189056);   //    131,072 B
    unsigned short* qT    = (unsigned short*)(ws + 14320128);   //  4,194,304 B
    unsigned short* kT    = (unsigned short*)(ws + 18514432);   //  4,194,304 B
    unsigned short* vT    = (unsigned short*)(ws + 22708736);   //  4,194,304 B
    unsigned short* attt  = (unsigned short*)(ws + 26903040);   //  4,194,304 B
    unsigned short* krwb  = (unsigned short*)(ws + 31097344);   //      4,096 B
    unsigned short* krhb  = (unsigned short*)(ws + 31101440);   //      4,096 B
    unsigned short* attTT = (unsigned short*)(ws + 31105536);   //  4,194,304 B

    k_prep<<<dim3(1568), dim3(256), 0, stream>>>(x, w_conv, w_qkv, w_att, krw, krh,
                                                 Xt, wt, wt2, krwb, krhb);
    k_gemm0<<<dim3(64, 16), dim3(256), 0, stream>>>(wt, Xt, out, qT, kT, vT,
                                                    b_conv, b_qkv);
    k_attn<<<dim3(1024), dim3(256), 0, stream>>>(qT, kT, vT, krwb, krhb, attTT);
    k_tr<<<dim3(512), dim3(256), 0, stream>>>(attTT, attt);
    k_gemm_s<<<dim3(128, 4), dim3(256), 0, stream>>>(wt2, attt, out, b_att);
}

// Round 10
// 178.384 us; speedup vs baseline: 1.1368x; 1.1368x over previous
//
#include <hip/hip_runtime.h>

// ---------------------------------------------------------------------------
// AttentionAugmentedConv2d: B=8, CIN=256, COUT=512, DK=DV=256, NH=8, H=W=32
//  k_prep   : fused Xt padded transpose + weight reorder
//  k_gemm0  : implicit-GEMM fused conv (128M x 64N, BK=64, 1024 blocks)
//  k_attn   : MFMA flash attention v6: K/V tiles staged to LDS once per BLOCK
//             (4 waves shared -> 4x less L2 traffic), double-buffered, one
//             barrier per tile; XOR chunk swizzle (gemm0 geometry); no online
//             max (logits << 88, fp32-safe); coalesced epilogue via LDS.
//             v4/v5 lesson: register-level prefetch gets sunk by the
//             allocator -> keep live ranges short, use LDS instead.
//  k_tr     : attT [256][8192] -> attt [8192][256]
//  k_gemm_s : 1x1 conv GEMM -> out ch 256..511
// reshape trap: att channel = h*32 + y, spatial = (x, d)
// ---------------------------------------------------------------------------

typedef __attribute__((ext_vector_type(8))) short short8;
typedef __attribute__((ext_vector_type(4))) float floatx4;

__device__ __forceinline__ unsigned short f2bf(float f) {
    unsigned int u = __float_as_uint(f);
    u += 0x7FFFu + ((u >> 16) & 1u);   // round-to-nearest-even
    return (unsigned short)(u >> 16);
}
__device__ __forceinline__ float bf2f(unsigned short s) {
    return __uint_as_float(((unsigned int)s) << 16);
}
__device__ __forceinline__ unsigned int pk2bf_trunc(float lo, float hi) {
    return (__float_as_uint(lo) >> 16) | (__float_as_uint(hi) & 0xFFFF0000u);
}
__device__ __forceinline__ unsigned int pk2bf_rne(float lo, float hi) {
    return (unsigned int)f2bf(lo) | ((unsigned int)f2bf(hi) << 16);
}
__device__ __forceinline__ void gload_lds16(const unsigned short* g, unsigned short* s) {
    __builtin_amdgcn_global_load_lds(
        (const __attribute__((address_space(1))) unsigned int*)g,
        (__attribute__((address_space(3))) unsigned int*)s, 16, 0, 0);
}

// ---------------- k_prep: fused Xt transpose + weight convert ---------------
__global__ __launch_bounds__(256) void k_prep(const float* __restrict__ x,
                                              const float* __restrict__ wc,
                                              const float* __restrict__ wq,
                                              const float* __restrict__ wa,
                                              const float* __restrict__ krw,
                                              const float* __restrict__ krh,
                                              unsigned short* __restrict__ Xt,
                                              unsigned short* __restrict__ wt,
                                              unsigned short* __restrict__ wt2,
                                              unsigned short* __restrict__ krwb,
                                              unsigned short* __restrict__ krhb) {
    __shared__ char smem[16896];
    const int tid = threadIdx.x;
    const int blk = blockIdx.x;
    if (blk < 272) {
        unsigned short* lds = (unsigned short*)smem;   // [ci][x] stride 33
        const int yy = blk % 34;
        const int b  = blk / 34;
        unsigned int* outp = (unsigned int*)(Xt + (((size_t)b * 34 + yy) * 34) * 256);
        if (yy == 0 || yy == 33) {
            for (int i = tid; i < 4352; i += 256) outp[i] = 0;
            return;
        }
        const int y = yy - 1;
        const float* xb = x + (size_t)b * 262144 + y * 32;
#pragma unroll
        for (int it = 0; it < 32; ++it) {
            const int e = it * 256 + tid;
            const int ci = e >> 5, xx = e & 31;
            lds[ci * 33 + xx] = f2bf(xb[ci * 1024 + xx]);
        }
        __syncthreads();
        const int ci2 = (tid & 127) * 2;
        const int xh = tid >> 7;
#pragma unroll
        for (int it = 0; it < 17; ++it) {
            const int xx = xh * 17 + it;
            unsigned int v = 0;
            if (xx >= 1 && xx <= 32)
                v = (unsigned int)lds[ci2 * 33 + xx - 1] |
                    ((unsigned int)lds[(ci2 + 1) * 33 + xx - 1] << 16);
            outp[xx * 128 + (tid & 127)] = v;
        }
    } else if (blk < 1296) {
        float* lw = (float*)smem;
        const int n = blk - 272;
        const float* src = (n < 256) ? (wc + (size_t)n * 2304)
                                     : (wq + (size_t)(n - 256) * 2304);
#pragma unroll
        for (int it = 0; it < 9; ++it)
            lw[it * 256 + tid] = src[it * 256 + tid];
        __syncthreads();
#pragma unroll
        for (int it = 0; it < 9; ++it) {
            const int kp = it * 256 + tid;
            const int g = kp >> 8, ci = kp & 255;
            wt[(size_t)n * 2304 + kp] = f2bf(lw[ci * 9 + g]);
        }
    } else {
        const int i = (blk - 1296) * 256 + tid;
        if (i < 65536)        wt2[i] = f2bf(wa[i]);
        else if (i < 67584) { const int j = i - 65536;
                              krwb[j] = (j < 2016) ? f2bf(krw[j]) : (unsigned short)0; }
        else if (i < 69632) { const int j = i - 67584;
                              krhb[j] = (j < 2016) ? f2bf(krh[j]) : (unsigned short)0; }
    }
}

// --------------- implicit-GEMM fused conv, 128M x 64N, BK=64 ----------------
__global__ __launch_bounds__(256, 4) void k_gemm0(const unsigned short* __restrict__ Wr,
                                                  const unsigned short* __restrict__ Xt,
                                                  float* __restrict__ out,
                                                  unsigned short* __restrict__ qT,
                                                  unsigned short* __restrict__ kT,
                                                  unsigned short* __restrict__ vT,
                                                  const float* __restrict__ bias_a,
                                                  const float* __restrict__ bias_b) {
    __shared__ unsigned short As[64 * 64];
    __shared__ unsigned short Bs[128 * 64];
    const int tid = threadIdx.x;
    const int lane = tid & 63, wv = tid >> 6;
    const int l15 = lane & 15, quad = lane >> 4;
    const int m0 = blockIdx.x * 128, n0 = blockIdx.y * 64;
    const int wave_m = (wv & 1) * 64, wave_n = (wv >> 1) * 32;
    floatx4 acc[2][4] = {};
    const int lr = lane >> 3;
    const int swz8 = ((lane & 7) ^ lr) * 8;
    const unsigned short* gA = Wr + (size_t)(n0 + wv * 16 + lr) * 2304 + swz8;
    int bb0[4];
#pragma unroll
    for (int r = 0; r < 4; ++r) {
        const int m = m0 + wv * 32 + r * 8 + lr;
        const int b = m >> 10, p = m & 1023, y = p >> 5, x = p & 31;
        bb0[r] = ((b * 34 + y) * 34 + x) * 256;
    }
    unsigned short* sA0 = As + wv * 1024;
    unsigned short* sB0 = Bs + wv * 2048;
    const int sw0 = ((quad)     ^ (l15 & 7)) * 8;
    const int sw1 = ((4 + quad) ^ (l15 & 7)) * 8;
    for (int k0 = 0; k0 < 2304; k0 += 64) {
        const int g = k0 >> 8;
        const int ci0 = k0 & 255;
        const int ky = g / 3, kx = g - ky * 3;
        const int offu = (ky * 34 + kx) * 256 + ci0 + swz8;
        __syncthreads();
        gload_lds16(gA + k0, sA0);
        gload_lds16(gA + (size_t)8 * 2304 + k0, sA0 + 512);
#pragma unroll
        for (int r = 0; r < 4; ++r)
            gload_lds16(Xt + bb0[r] + offu, sB0 + r * 512);
        __syncthreads();
#pragma unroll
        for (int h = 0; h < 2; ++h) {
            const int sw = h ? sw1 : sw0;
            short8 a[2], b[4];
#pragma unroll
            for (int i = 0; i < 2; ++i)
                a[i] = *reinterpret_cast<const short8*>(As + (wave_n + i * 16 + l15) * 64 + sw);
#pragma unroll
            for (int j = 0; j < 4; ++j)
                b[j] = *reinterpret_cast<const short8*>(Bs + (wave_m + j * 16 + l15) * 64 + sw);
#pragma unroll
            for (int i = 0; i < 2; ++i)
#pragma unroll
                for (int j = 0; j < 4; ++j)
                    acc[i][j] = __builtin_amdgcn_mfma_f32_16x16x32_bf16(a[i], b[j], acc[i][j], 0, 0, 0);
        }
    }
#pragma unroll
    for (int i = 0; i < 2; ++i)
#pragma unroll
        for (int jj = 0; jj < 4; ++jj)
#pragma unroll
            for (int rg = 0; rg < 4; ++rg) {
                const int n = n0 + wave_n + i * 16 + quad * 4 + rg;
                const int m = m0 + wave_m + jj * 16 + l15;
                const float v = acc[i][jj][rg];
                const int bb = m >> 10, p = m & 1023;
                if (n < 256) {
                    out[(size_t)bb * 524288 + (size_t)n * 1024 + p] = v + bias_a[n];
                } else {
                    const int c = n - 256;
                    const float vq = v + bias_b[c];
                    if (c < 256) {
                        const int h = c >> 5, d = c & 31;
                        qT[(((size_t)(bb * 8 + h)) * 1024 + p) * 32 + d] =
                            f2bf(vq * 0.17677669529663687f);
                    } else if (c < 512) {
                        const int c2 = c - 256;
                        const int h = c2 >> 5, d = c2 & 31;
                        kT[(((size_t)(bb * 8 + h)) * 1024 + p) * 32 + d] = f2bf(vq);
                    } else {
                        const int c2 = c - 512;
                        const int h = c2 >> 5, d = c2 & 31;
                        vT[(((size_t)(bb * 8 + h)) * 32 + d) * 1024 + p] = f2bf(vq);
                    }
                }
            }
}

// --------------- MFMA flash attention v6: LDS-shared K/V --------------------
// bid = qt*64 + bh (XCD locality). Per tile (64 keys): K 4KB + V 4KB staged to
// LDS via global_load_lds (2 insts/wave), double-buffered, ONE barrier/tile.
// LDS rows = 128 B (8 chunks of 16 B), phys chunk = logical ^ (row&7).
// mfma: D[i][j]=sum_k A[i][k]B[j][k]; frag lane holds X[l15][quad*8+:8];
// D lane holds D[quad*4+r][l15].
__global__ __launch_bounds__(256, 3) void k_attn(const unsigned short* __restrict__ qT,
                                                 const unsigned short* __restrict__ kT,
                                                 const unsigned short* __restrict__ vT,
                                                 const unsigned short* __restrict__ krwb,
                                                 const unsigned short* __restrict__ krhb,
                                                 unsigned short* __restrict__ attT) {
    __shared__ unsigned short Ks[2][2048];     // K tile: 32 rows x 64 elems
    __shared__ unsigned short Vs[2][2048];     // V tile: 32 d-rows x 64 elems
    __shared__ float rh_s[64 * 68];            // [q_local][m'] stride 68 fp32
    __shared__ unsigned short Pw[4 * 1152];    // per-wave P (stride 72)
    const int tid = threadIdx.x;
    const int lane = tid & 63, wv = tid >> 6;
    const int l15 = lane & 15, quad = lane >> 4;
    const int bid = blockIdx.x;
    const int bh = bid & 63;                   // XCD swizzle: bid%8 == h
    const int qt = bid >> 6;
    const int h = bh & 7;
    const int b = bh >> 3;
    const unsigned short* qbase = qT + (size_t)bh * 32768;
    const unsigned short* kbase = kT + (size_t)bh * 32768;
    const unsigned short* vbase = vT + (size_t)bh * 32768;
    const int qloc = wv * 16 + l15;
    const int pq = qt * 64 + qloc;
    const int yq = pq >> 5, xq = pq & 31;

    const short8 qfrag = *reinterpret_cast<const short8*>(
        qbase + (size_t)pq * 32 + quad * 8);
    const floatx4 zero = {0.f, 0.f, 0.f, 0.f};
    unsigned short* pw = Pw + wv * 1152;

    // staging lanes: row-in-8-group + swizzled chunk (gemm0 geometry)
    const int lr8 = lane >> 3, lc8 = lane & 7;
    const int swz = (lc8 ^ lr8) * 8;           // source chunk offset (elems)
    const unsigned short* ksrc = kbase + wv * 512 + lr8 * 64 + swz;     // +nt*2048
    const unsigned short* vsrc = vbase + (size_t)(wv * 8 + lr8) * 1024 + swz; // +nt*64
    unsigned short* kdst0 = &Ks[0][wv * 512];
    unsigned short* kdst1 = &Ks[1][wv * 512];
    unsigned short* vdst0 = &Vs[0][wv * 512];
    unsigned short* vdst1 = &Vs[1][wv * 512];

    // rel tables via mfma: Rel[m'][q] = krX[m'] . Q[q]
#pragma unroll
    for (int sub = 0; sub < 4; ++sub) {
        const short8 aw = *reinterpret_cast<const short8*>(krwb + (sub * 16 + l15) * 32 + quad * 8);
        const short8 ah = *reinterpret_cast<const short8*>(krhb + (sub * 16 + l15) * 32 + quad * 8);
        const floatx4 dw = __builtin_amdgcn_mfma_f32_16x16x32_bf16(aw, qfrag, zero, 0, 0, 0);
        const floatx4 dh = __builtin_amdgcn_mfma_f32_16x16x32_bf16(ah, qfrag, zero, 0, 0, 0);
        *reinterpret_cast<floatx4*>(rh_s + qloc * 68 + sub * 16 + quad * 4) = dh;
        uint2 uu;
        uu.x = pk2bf_rne(dw[0], dw[1]);
        uu.y = pk2bf_rne(dw[2], dw[3]);
        *reinterpret_cast<uint2*>(pw + l15 * 64 + sub * 16 + quad * 4) = uu;
    }
    float rwreg[8];
#pragma unroll
    for (int j = 0; j < 8; ++j) {
        const int xn = (j >> 2) * 16 + quad * 4 + (j & 3);
        rwreg[j] = bf2f(pw[l15 * 64 + xn - xq + 31]);
    }
    asm volatile("s_waitcnt lgkmcnt(0)" ::: "memory");  // pw safe to reuse for P

    const float* rhq = rh_s + qloc * 68 + 31 - yq;
    float lsum = 0.f;
    floatx4 O0 = zero, O1 = zero;              // O[d][q]: d=quad*4+r (+16), q=l15

    // prologue: stage tile 0
    gload_lds16(ksrc, kdst0);
    gload_lds16(vsrc, vdst0);
    __syncthreads();

    // frag-read swizzled offsets
    const int krow = (l15 >> 1);               // row&7 for K rows sub*8+(l15>>1)
    const int kchunkbase = (l15 & 1) * 4;
    const int vsw0 = ((quad)     ^ (l15 & 7)) * 8;
    const int vsw1 = ((4 + quad) ^ (l15 & 7)) * 8;

    for (int nt = 0; nt < 16; ++nt) {
        const unsigned short* Kc = Ks[nt & 1];
        const unsigned short* Vc = Vs[nt & 1];
        // stage next tile (drained by end-of-iteration barrier)
        if (nt < 15) {
            gload_lds16(ksrc + (nt + 1) * 2048, (nt & 1) ? kdst0 : kdst1);
            gload_lds16(vsrc + (nt + 1) * 64,  (nt & 1) ? vdst0 : vdst1);
        }
        // K frags from LDS + QK
        floatx4 d[4];
#pragma unroll
        for (int sub = 0; sub < 4; ++sub) {
            const int row = sub * 8 + krow;
            const short8 kf = *reinterpret_cast<const short8*>(
                Kc + row * 64 + ((kchunkbase + quad) ^ krow) * 8);
            d[sub] = __builtin_amdgcn_mfma_f32_16x16x32_bf16(kf, qfrag, zero, 0, 0, 0);
        }
        const float rh0 = rhq[nt * 2];
        const float rh1 = rhq[nt * 2 + 1];
        // p = exp(score); per-lane l accumulation; write P bf16 (truncate)
#pragma unroll
        for (int sub = 0; sub < 4; ++sub) {
            const float rhv = (sub >> 1) ? rh1 : rh0;
            const float p0 = __expf(d[sub][0] + rwreg[(sub & 1) * 4 + 0] + rhv);
            const float p1 = __expf(d[sub][1] + rwreg[(sub & 1) * 4 + 1] + rhv);
            const float p2 = __expf(d[sub][2] + rwreg[(sub & 1) * 4 + 2] + rhv);
            const float p3 = __expf(d[sub][3] + rwreg[(sub & 1) * 4 + 3] + rhv);
            lsum += (p0 + p1) + (p2 + p3);
            uint2 uu;
            uu.x = pk2bf_trunc(p0, p1);
            uu.y = pk2bf_trunc(p2, p3);
            *reinterpret_cast<uint2*>(pw + l15 * 72 + sub * 16 + quad * 4) = uu;
        }
        asm volatile("s_waitcnt lgkmcnt(0)" ::: "memory");  // P visible (same wave)
        const short8 pf0 = *reinterpret_cast<const short8*>(pw + l15 * 72 + quad * 8);
        const short8 pf1 = *reinterpret_cast<const short8*>(pw + l15 * 72 + 32 + quad * 8);
        // V frags from LDS + PV
        const short8 vf0 = *reinterpret_cast<const short8*>(Vc + l15 * 64 + vsw0);
        const short8 vf1 = *reinterpret_cast<const short8*>(Vc + (16 + l15) * 64 + vsw0);
        const short8 vf2 = *reinterpret_cast<const short8*>(Vc + l15 * 64 + vsw1);
        const short8 vf3 = *reinterpret_cast<const short8*>(Vc + (16 + l15) * 64 + vsw1);
        O0 = __builtin_amdgcn_mfma_f32_16x16x32_bf16(vf0, pf0, O0, 0, 0, 0);
        O1 = __builtin_amdgcn_mfma_f32_16x16x32_bf16(vf1, pf0, O1, 0, 0, 0);
        O0 = __builtin_amdgcn_mfma_f32_16x16x32_bf16(vf2, pf1, O0, 0, 0, 0);
        O1 = __builtin_amdgcn_mfma_f32_16x16x32_bf16(vf3, pf1, O1, 0, 0, 0);
        __syncthreads();   // drains stage vmcnt; all waves done with Kc/Vc
    }
    lsum += __shfl_xor(lsum, 16);
    lsum += __shfl_xor(lsum, 32);
    const float inv = 1.0f / lsum;
    // coalesced epilogue: O -> LDS (reuse Ks as Ob[2][1024]) -> 2x2KB rows
    unsigned short* Ob = &Ks[0][0];
    {
        const int row = wv >> 1;
        const int xql = (wv & 1) * 16 + l15;
        uint2 o0, o1;
        o0.x = pk2bf_rne(O0[0] * inv, O0[1] * inv);
        o0.y = pk2bf_rne(O0[2] * inv, O0[3] * inv);
        o1.x = pk2bf_rne(O1[0] * inv, O1[1] * inv);
        o1.y = pk2bf_rne(O1[2] * inv, O1[3] * inv);
        *reinterpret_cast<uint2*>(Ob + row * 1024 + xql * 32 + quad * 4) = o0;
        *reinterpret_cast<uint2*>(Ob + row * 1024 + xql * 32 + 16 + quad * 4) = o1;
    }
    __syncthreads();
    // attT[ci = h*32 + qt*2 + row][b*1024 + 0..1023], 16B per thread
    {
        const int row = tid >> 7, c16 = tid & 127;
        *reinterpret_cast<uint4*>(
            attT + ((size_t)(h * 32 + qt * 2 + row)) * 8192 + b * 1024 + c16 * 8) =
            *reinterpret_cast<const uint4*>(Ob + row * 1024 + c16 * 8);
    }
}

// --------------- attT [256][8192] -> attt [8192][256] -----------------------
__global__ __launch_bounds__(256) void k_tr(const unsigned short* __restrict__ src,
                                            unsigned short* __restrict__ dst) {
    __shared__ unsigned short t[64 * 72];
    const int tid = threadIdx.x;
    const int m0 = (blockIdx.x & 127) * 64;
    const int k0 = (blockIdx.x >> 7) * 64;
#pragma unroll
    for (int i = 0; i < 2; ++i) {
        const int idx = i * 256 + tid;
        const int k = idx >> 3, c8 = (idx & 7) * 8;
        *reinterpret_cast<uint4*>(t + k * 72 + c8) =
            *reinterpret_cast<const uint4*>(src + (size_t)(k0 + k) * 8192 + m0 + c8);
    }
    __syncthreads();
#pragma unroll
    for (int i = 0; i < 2; ++i) {
        const int idx = i * 256 + tid;
        const int m = idx >> 3, c8 = (idx & 7) * 8;
        unsigned short v[8];
#pragma unroll
        for (int j = 0; j < 8; ++j) v[j] = t[(c8 + j) * 72 + m];
        *reinterpret_cast<uint4*>(dst + (size_t)(m0 + m) * 256 + k0 + c8) =
            *reinterpret_cast<uint4*>(v);
    }
}

// --------------- small 64-tile GEMM for the 1x1 conv ------------------------
__global__ __launch_bounds__(256) void k_gemm_s(const unsigned short* __restrict__ Wm,
                                                const unsigned short* __restrict__ Dm,
                                                float* __restrict__ out,
                                                const float* __restrict__ bias) {
    __shared__ unsigned short As[64 * 40];
    __shared__ unsigned short Bs[64 * 40];
    const int tid = threadIdx.x;
    const int m0 = blockIdx.x * 64, n0 = blockIdx.y * 64;
    const int lane = tid & 63;
    const int wv = tid >> 6;
    const int l15 = lane & 15, quad = lane >> 4;
    const int n_off = (wv & 1) * 32, m_off = (wv >> 1) * 32;
    floatx4 acc[2][2] = {};
    const int r = tid >> 2, c8 = (tid & 3) * 8;
    const unsigned short* gA = Wm + (size_t)(n0 + r) * 256 + c8;
    const unsigned short* gB = Dm + (size_t)(m0 + r) * 256 + c8;
    unsigned short* sA = As + r * 40 + c8;
    unsigned short* sB = Bs + r * 40 + c8;
    for (int k0 = 0; k0 < 256; k0 += 32) {
        __syncthreads();
        *reinterpret_cast<uint4*>(sA) = *reinterpret_cast<const uint4*>(gA + k0);
        *reinterpret_cast<uint4*>(sB) = *reinterpret_cast<const uint4*>(gB + k0);
        __syncthreads();
        const short8 a0 = *reinterpret_cast<const short8*>(As + (n_off +      l15) * 40 + quad * 8);
        const short8 a1 = *reinterpret_cast<const short8*>(As + (n_off + 16 + l15) * 40 + quad * 8);
        const short8 b0 = *reinterpret_cast<const short8*>(Bs + (m_off +      l15) * 40 + quad * 8);
        const short8 b1 = *reinterpret_cast<const short8*>(Bs + (m_off + 16 + l15) * 40 + quad * 8);
        acc[0][0] = __builtin_amdgcn_mfma_f32_16x16x32_bf16(a0, b0, acc[0][0], 0, 0, 0);
        acc[0][1] = __builtin_amdgcn_mfma_f32_16x16x32_bf16(a0, b1, acc[0][1], 0, 0, 0);
        acc[1][0] = __builtin_amdgcn_mfma_f32_16x16x32_bf16(a1, b0, acc[1][0], 0, 0, 0);
        acc[1][1] = __builtin_amdgcn_mfma_f32_16x16x32_bf16(a1, b1, acc[1][1], 0, 0, 0);
    }
#pragma unroll
    for (int i = 0; i < 2; ++i)
#pragma unroll
        for (int jj = 0; jj < 2; ++jj)
#pragma unroll
            for (int rg = 0; rg < 4; ++rg) {
                const int n = n0 + n_off + i * 16 + quad * 4 + rg;
                const int m = m0 + m_off + jj * 16 + l15;
                const int bb = m >> 10, p = m & 1023;
                out[(size_t)bb * 524288 + (size_t)(n + 256) * 1024 + p] =
                    acc[i][jj][rg] + bias[n];
            }
}

// ---------------------------------------------------------------------------
extern "C" void kernel_launch(void* const* d_in, const int* in_sizes, int n_in,
                              void* d_out, int out_size, void* d_ws, size_t ws_size,
                              hipStream_t stream) {
    const float* x      = (const float*)d_in[0];
    const float* w_conv = (const float*)d_in[1];
    const float* b_conv = (const float*)d_in[2];
    const float* w_qkv  = (const float*)d_in[3];
    const float* b_qkv  = (const float*)d_in[4];
    const float* w_att  = (const float*)d_in[5];
    const float* b_att  = (const float*)d_in[6];
    const float* krw    = (const float*)d_in[7];
    const float* krh    = (const float*)d_in[8];
    float* out = (float*)d_out;

    char* ws = (char*)d_ws;
    unsigned short* Xt    = (unsigned short*)(ws);              //  4,734,976 B
    unsigned short* wt    = (unsigned short*)(ws + 9470464);    //  4,718,592 B
    unsigned short* wt2   = (unsigned short*)(ws + 14189056);   //    131,072 B
    unsigned short* qT    = (unsigned short*)(ws + 14320128);   //  4,194,304 B
    unsigned short* kT    = (unsigned short*)(ws + 18514432);   //  4,194,304 B
    unsigned short* vT    = (unsigned short*)(ws + 22708736);   //  4,194,304 B
    unsigned short* attt  = (unsigned short*)(ws + 26903040);   //  4,194,304 B
    unsigned short* krwb  = (unsigned short*)(ws + 31097344);   //      4,096 B
    unsigned short* krhb  = (unsigned short*)(ws + 31101440);   //      4,096 B
    unsigned short* attTT = (unsigned short*)(ws + 31105536);   //  4,194,304 B

    k_prep<<<dim3(1568), dim3(256), 0, stream>>>(x, w_conv, w_qkv, w_att, krw, krh,
                                                 Xt, wt, wt2, krwb, krhb);
    k_gemm0<<<dim3(64, 16), dim3(256), 0, stream>>>(wt, Xt, out, qT, kT, vT,
                                                    b_conv, b_qkv);
    k_attn<<<dim3(1024), dim3(256), 0, stream>>>(qT, kT, vT, krwb, krhb, attTT);
    k_tr<<<dim3(512), dim3(256), 0, stream>>>(attTT, attt);
    k_gemm_s<<<dim3(128, 4), dim3(256), 0, stream>>>(wt2, attt, out, b_att);
}